// Round 3
// baseline (229.022 us; speedup 1.0000x reference)
//
#include <hip/hip_runtime.h>

#define NN 100000
#define EE 1600000
#define DIN 128
#define DH 64
#define DOUT 32

#define BSH 8                      // bucket = dst >> 8  (256 nodes/bucket)
#define BNODES 256
#define NBUCK ((NN + BNODES - 1) / BNODES)   // 391
#define BCAP 4608                  // fixed bucket capacity (mean 4096 + 8 sigma)
#define CHUNK 4096                 // edges per Pass-A workgroup
#define NCHUNK ((EE + CHUNK - 1) / CHUNK)    // 391

typedef unsigned short ush;
typedef __attribute__((ext_vector_type(8))) short bf16x8;
typedef __attribute__((ext_vector_type(4))) float f32x4;
typedef __attribute__((ext_vector_type(2))) float f32x2;

__device__ __forceinline__ float bflo(unsigned u) {
    union { unsigned u; float f; } c; c.u = u << 16; return c.f;
}
__device__ __forceinline__ float bfhi(unsigned u) {
    union { unsigned u; float f; } c; c.u = u & 0xffff0000u; return c.f;
}
__device__ __forceinline__ ush f2bf(float f) {
    union { float f; unsigned u; } c; c.f = f;
    unsigned r = c.u + 0x7fff + ((c.u >> 16) & 1);   // round-to-nearest-even
    return (ush)(r >> 16);
}

// -------- packed dual-f32 ops (CDNA VOP3P: add/mul/fma only — NO pk_max!) --------
__device__ __forceinline__ void pka(f32x2& a, f32x2 b) {          // a += b
    asm("v_pk_add_f32 %0, %0, %1" : "+v"(a) : "v"(b));
}
__device__ __forceinline__ void pkfma(f32x2& d, f32x2 a, f32x2 b) { // d += a*b
    asm("v_pk_fma_f32 %0, %1, %2, %0" : "+v"(d) : "v"(a), "v"(b));
}
__device__ __forceinline__ void pkmul(f32x2& a, f32x2 b) {        // a *= b
    asm("v_pk_mul_f32 %0, %0, %1" : "+v"(a) : "v"(b));
}
__device__ __forceinline__ f32x2 up2(unsigned u) {                // (bf16 lo, bf16 hi) -> 2 f32
    f32x2 p; p.x = bflo(u); p.y = bfhi(u); return p;
}

// ---------------- init bucket cursors to fixed bases ----------------
__global__ void init_bcur_kernel(int* __restrict__ bcur) {
    int i = blockIdx.x * 256 + threadIdx.x;
    if (i < NBUCK) bcur[i] = i * BCAP;
}

// ---------------- Pass A: bin edges into fixed-capacity buckets (packed (src<<8)|dstlow)
__global__ __launch_bounds__(256) void binA_kernel(const int* __restrict__ src,
                                                   const int* __restrict__ dst,
                                                   int* __restrict__ bcur,
                                                   unsigned* __restrict__ tmp) {
    __shared__ int hist[NBUCK];
    __shared__ int scn[NBUCK];      // exclusive scan (staging base per bucket)
    __shared__ int cur[NBUCK];      // staging cursor
    __shared__ int gb[NBUCK];       // global base - scn  (addr = gb[b] + lp)
    __shared__ int s2[256];
    __shared__ unsigned staged[CHUNK];
    __shared__ int gaddr[CHUNK];
    int t = threadIdx.x;
    for (int i = t; i < NBUCK; i += 256) hist[i] = 0;
    __syncthreads();
    int e0 = blockIdx.x * CHUNK;
    int nE = min(CHUNK, EE - e0);

    int my_e[16], my_bk[16];
#pragma unroll
    for (int k = 0; k < 16; k++) {
        int li = t + k * 256;
        bool ok = li < nE;
        int idx = ok ? (e0 + li) : e0;
        int d = dst[idx];
        int s = src[idx];
        int b = d >> BSH;
        my_e[k] = (s << 8) | (d & 255);
        my_bk[k] = ok ? b : -1;
        if (ok) atomicAdd(&hist[b], 1);
    }
    __syncthreads();
    int a0 = (2 * t < NBUCK) ? hist[2 * t] : 0;
    int a1 = (2 * t + 1 < NBUCK) ? hist[2 * t + 1] : 0;
    s2[t] = a0 + a1;
    __syncthreads();
    for (int off = 1; off < 256; off <<= 1) {
        int x = (t >= off) ? s2[t - off] : 0;
        __syncthreads();
        s2[t] += x;
        __syncthreads();
    }
    int excl = s2[t] - a0 - a1;
    if (2 * t < NBUCK)     { scn[2 * t] = excl;          cur[2 * t] = excl; }
    if (2 * t + 1 < NBUCK) { scn[2 * t + 1] = excl + a0; cur[2 * t + 1] = excl + a0; }
    __syncthreads();
    for (int i = t; i < NBUCK; i += 256) {
        int h = hist[i];
        if (h) gb[i] = atomicAdd(&bcur[i], h) - scn[i];
    }
    __syncthreads();
#pragma unroll
    for (int k = 0; k < 16; k++) {
        int b = my_bk[k];
        if (b >= 0) {
            int lp = atomicAdd(&cur[b], 1);
            staged[lp] = (unsigned)my_e[k];
            gaddr[lp] = gb[b] + lp;
        }
    }
    __syncthreads();
    for (int i = t; i < nE; i += 256)
        tmp[gaddr[i]] = staged[i];
}

// ---------------- Pass B: per-bucket node histogram + scan -> offs/ends/dinv/csr -------
__global__ __launch_bounds__(256) void binB_kernel(const unsigned* __restrict__ tmp,
                                                   const int* __restrict__ bcur,
                                                   int* __restrict__ csr,
                                                   int* __restrict__ offs,
                                                   int* __restrict__ ends,
                                                   float* __restrict__ dinv) {
    __shared__ int hist[BNODES], cur[BNODES], sc[BNODES];
    int b = blockIdx.x, t = threadIdx.x;
    int e0 = b * BCAP, e1 = bcur[b];
    hist[t] = 0;
    __syncthreads();
    for (int i = e0 + t; i < e1; i += 256) atomicAdd(&hist[tmp[i] & 255], 1);
    __syncthreads();
    int v = hist[t];
    sc[t] = v;
    __syncthreads();
    for (int off = 1; off < 256; off <<= 1) {
        int x = (t >= off) ? sc[t - off] : 0;
        __syncthreads();
        sc[t] += x;
        __syncthreads();
    }
    int excl = sc[t] - v;
    cur[t] = e0 + excl;
    int node = (b << BSH) + t;
    if (node < NN) {
        offs[node] = e0 + excl;
        ends[node] = e0 + excl + v;
        dinv[node] = 1.0f / sqrtf((float)v + 1.0f);
    }
    __syncthreads();
    for (int i = e0 + t; i < e1; i += 256) {
        unsigned u = tmp[i];
        int pos = atomicAdd(&cur[u & 255], 1);
        csr[pos] = (int)(u >> 8);
    }
}

// ---------------- MFMA GEMM + dinv-scale, bf16 out: Y = bf16((X@W)*dinv) -------------
template <int K, int NC, typename XT>
__global__ __launch_bounds__(256) void gemm_mfma_kernel(const XT* __restrict__ X,
                                                        const float* __restrict__ W,
                                                        const float* __restrict__ dinv,
                                                        ush* __restrict__ Y) {
    constexpr int GROWS = 128;
    constexpr int KP = K + 8;            // pad: row stride odd multiple of 16B
    constexpr int NKC = K / 32;          // k-chunks
    constexpr int NCT = NC / 16;         // col tiles
    __shared__ __align__(16) ush Xl[GROWS * KP];
    __shared__ __align__(16) ush Wt[NC * KP];
    const int t = threadIdx.x;
    const int row0 = blockIdx.x * GROWS;

    if constexpr (sizeof(XT) == 4) {
        for (int i = t; i < GROWS * (K / 4); i += 256) {
            int r = i / (K / 4), c4 = i % (K / 4);
            int row = row0 + r;
            float4 v = make_float4(0.f, 0.f, 0.f, 0.f);
            if (row < NN) v = *(const float4*)&X[(size_t)row * K + c4 * 4];
            ushort4 o;
            o.x = f2bf(v.x); o.y = f2bf(v.y); o.z = f2bf(v.z); o.w = f2bf(v.w);
            *(ushort4*)&Xl[r * KP + c4 * 4] = o;
        }
    } else {
        for (int i = t; i < GROWS * (K / 8); i += 256) {
            int r = i / (K / 8), c8 = i % (K / 8);
            int row = row0 + r;
            uint4 v = make_uint4(0, 0, 0, 0);
            if (row < NN) v = *(const uint4*)&X[(size_t)row * K + c8 * 8];
            *(uint4*)&Xl[r * KP + c8 * 8] = v;
        }
    }
    for (int i = t; i < K * (NC / 4); i += 256) {
        int k = i / (NC / 4), n4 = i % (NC / 4);
        float4 v = *(const float4*)&W[k * NC + n4 * 4];
        Wt[(n4 * 4 + 0) * KP + k] = f2bf(v.x);
        Wt[(n4 * 4 + 1) * KP + k] = f2bf(v.y);
        Wt[(n4 * 4 + 2) * KP + k] = f2bf(v.z);
        Wt[(n4 * 4 + 3) * KP + k] = f2bf(v.w);
    }
    __syncthreads();

    const int wave = t >> 6, lane = t & 63;
    const int m = lane & 15, quad = lane >> 4;
    const int wrow = wave * 32;

    f32x4 acc[2][NCT];
#pragma unroll
    for (int rt = 0; rt < 2; rt++)
#pragma unroll
        for (int ct = 0; ct < NCT; ct++) acc[rt][ct] = (f32x4){0.f, 0.f, 0.f, 0.f};

#pragma unroll
    for (int kc = 0; kc < NKC; kc++) {
        int koff = kc * 32 + quad * 8;
        bf16x8 b[NCT];
#pragma unroll
        for (int ct = 0; ct < NCT; ct++)
            b[ct] = *(const bf16x8*)&Wt[(ct * 16 + m) * KP + koff];
#pragma unroll
        for (int rt = 0; rt < 2; rt++) {
            bf16x8 a = *(const bf16x8*)&Xl[(wrow + rt * 16 + m) * KP + koff];
#pragma unroll
            for (int ct = 0; ct < NCT; ct++)
                acc[rt][ct] = __builtin_amdgcn_mfma_f32_16x16x32_bf16(a, b[ct], acc[rt][ct], 0, 0, 0);
        }
    }
#pragma unroll
    for (int rt = 0; rt < 2; rt++) {
#pragma unroll
        for (int reg = 0; reg < 4; reg++) {
            int row = row0 + wrow + rt * 16 + quad * 4 + reg;
            if (row < NN) {
                float s = dinv[row];
#pragma unroll
                for (int ct = 0; ct < NCT; ct++)
                    Y[(size_t)row * NC + ct * 16 + m] = f2bf(acc[rt][ct][reg] * s);
            }
        }
    }
}

// packed accumulate of a 4-uint (8 bf16) row chunk into 4 f32x2 accumulators
#define ACCP(u4) { pka(ac0, up2(u4.x)); pka(ac1, up2(u4.y)); \
                   pka(ac2, up2(u4.z)); pka(ac3, up2(u4.w)); }

#define BFLY(msk) { f32x2 t_;                                           \
    t_.x = __shfl_xor(ac0.x, msk); t_.y = __shfl_xor(ac0.y, msk); pka(ac0, t_); \
    t_.x = __shfl_xor(ac1.x, msk); t_.y = __shfl_xor(ac1.y, msk); pka(ac1, t_); \
    t_.x = __shfl_xor(ac2.x, msk); t_.y = __shfl_xor(ac2.y, msk); pka(ac2, t_); \
    t_.x = __shfl_xor(ac3.x, msk); t_.y = __shfl_xor(ac3.y, msk); pka(ac3, t_); }

// ---------------- gather1 + gemm2 fused (F=64 bf16): 2 nodes/wave, 4 slots x 8 fgroups.
// Gather uses v_pk_add_f32 (2 feats/inst). Epilogue: h kept in f32 (no bf16 roundtrip,
// strictly more accurate), W2 staged f32 as per-lane 8x8 partitions (272B stride),
// 64 MACs done as 32 v_pk_fma_f32 per lane. h1 never touches memory.
__global__ __launch_bounds__(256) void gather1_fused_kernel(const int* __restrict__ offs,
                                                            const int* __restrict__ ends,
                                                            const float* __restrict__ dinv,
                                                            const ush* __restrict__ Hs,
                                                            const int* __restrict__ csr,
                                                            const float* __restrict__ b1,
                                                            const float* __restrict__ W2,
                                                            ush* __restrict__ Hs2) {
    // lane l (=lane&31, fg=l&7, es=l>>3) owns W2 rows fg*8..+8, cols es*8..+8 as a
    // contiguous 64-float block; stride 68 floats (272B) staggers lanes across banks.
    __shared__ __align__(16) float Wp[32 * 68];
    {
        int t = threadIdx.x;            // 2048 floats / 256 threads = 8 floats each
        int lp = t >> 3, r = t & 7;
        int srow = (lp & 7) * 8 + r, scol = (lp >> 3) * 8;
        float4 va = *(const float4*)&W2[srow * DOUT + scol];
        float4 vb = *(const float4*)&W2[srow * DOUT + scol + 4];
        *(float4*)&Wp[lp * 68 + r * 8] = va;
        *(float4*)&Wp[lp * 68 + r * 8 + 4] = vb;
    }
    __syncthreads();

    int wid = (blockIdx.x * 256 + threadIdx.x) >> 6;
    int lane = threadIdx.x & 63;
    int node = wid * 2 + (lane >> 5);
    if (node >= NN) return;
    int l = lane & 31;
    int es = l >> 3;                     // 4 edge slots (stride 4)
    int fg = l & 7;                      // 8 fgroups x 8 bf16 = 16 B
    int start = offs[node], end = ends[node];
    float dv = dinv[node];                                   // hoisted
    uint4 su = *(const uint4*)&Hs[node * DH + fg * 8];       // hoisted self-row
    f32x2 ac0 = {0.f, 0.f}, ac1 = {0.f, 0.f}, ac2 = {0.f, 0.f}, ac3 = {0.f, 0.f};
    int k = start + es;
    for (; k + 12 < end; k += 16) {      // 4 independent rows in flight per lane
        int s0 = csr[k], s1 = csr[k + 4], s2 = csr[k + 8], s3 = csr[k + 12];
        uint4 u0 = *(const uint4*)&Hs[s0 * DH + fg * 8];
        uint4 u1 = *(const uint4*)&Hs[s1 * DH + fg * 8];
        uint4 u2 = *(const uint4*)&Hs[s2 * DH + fg * 8];
        uint4 u3 = *(const uint4*)&Hs[s3 * DH + fg * 8];
        ACCP(u0) ACCP(u1) ACCP(u2) ACCP(u3)
    }
    for (; k < end; k += 4) {
        int s = csr[k];
        uint4 u = *(const uint4*)&Hs[s * DH + fg * 8];
        ACCP(u)
    }
    // butterfly over es (bits 3,4): every lane gets full neighbor sums for its fgroup
    BFLY(8) BFLY(16)

    float4 ba = *(const float4*)&b1[fg * 8];
    float4 bb = *(const float4*)&b1[fg * 8 + 4];
    f32x2 dvp; dvp.x = dv; dvp.y = dv;
    // h = relu(dv*(acc + self) + b1), pure f32 (no bf16 roundtrip)
    pka(ac0, up2(su.x)); pka(ac1, up2(su.y)); pka(ac2, up2(su.z)); pka(ac3, up2(su.w));
    f32x2 h0; h0.x = ba.x; h0.y = ba.y;
    f32x2 h1; h1.x = ba.z; h1.y = ba.w;
    f32x2 h2; h2.x = bb.x; h2.y = bb.y;
    f32x2 h3; h3.x = bb.z; h3.y = bb.w;
    pkfma(h0, dvp, ac0); pkfma(h1, dvp, ac1); pkfma(h2, dvp, ac2); pkfma(h3, dvp, ac3);
    h0.x = fmaxf(h0.x, 0.f); h0.y = fmaxf(h0.y, 0.f);
    h1.x = fmaxf(h1.x, 0.f); h1.y = fmaxf(h1.y, 0.f);
    h2.x = fmaxf(h2.x, 0.f); h2.y = fmaxf(h2.y, 0.f);
    h3.x = fmaxf(h3.x, 0.f); h3.y = fmaxf(h3.y, 0.f);

    // per-lane 8x8 block of h1@W2: p[c-pair] += h[r] * W2[fg*8+r][es*8 + c-pair]
    const float* wl = &Wp[l * 68];
    float hs_[8] = {h0.x, h0.y, h1.x, h1.y, h2.x, h2.y, h3.x, h3.y};
    f32x2 p0 = {0.f, 0.f}, p1 = {0.f, 0.f}, p2 = {0.f, 0.f}, p3 = {0.f, 0.f};
#pragma unroll
    for (int r = 0; r < 8; r++) {
        float4 wa = *(const float4*)&wl[r * 8];
        float4 wb = *(const float4*)&wl[r * 8 + 4];
        f32x2 hr; hr.x = hs_[r]; hr.y = hs_[r];
        f32x2 w01; w01.x = wa.x; w01.y = wa.y;
        f32x2 w23; w23.x = wa.z; w23.y = wa.w;
        f32x2 w45; w45.x = wb.x; w45.y = wb.y;
        f32x2 w67; w67.x = wb.z; w67.y = wb.w;
        pkfma(p0, hr, w01); pkfma(p1, hr, w23);
        pkfma(p2, hr, w45); pkfma(p3, hr, w67);
    }
    // butterfly over fg (bits 0..2): full column sums on every lane
#pragma unroll
    for (int msk = 1; msk <= 4; msk <<= 1) {
        f32x2 t_;
        t_.x = __shfl_xor(p0.x, msk); t_.y = __shfl_xor(p0.y, msk); pka(p0, t_);
        t_.x = __shfl_xor(p1.x, msk); t_.y = __shfl_xor(p1.y, msk); pka(p1, t_);
        t_.x = __shfl_xor(p2.x, msk); t_.y = __shfl_xor(p2.y, msk); pka(p2, t_);
        t_.x = __shfl_xor(p3.x, msk); t_.y = __shfl_xor(p3.y, msk); pka(p3, t_);
    }
    if (fg == 0) {
        pkmul(p0, dvp); pkmul(p1, dvp); pkmul(p2, dvp); pkmul(p3, dvp);
        ushort4 oa, ob;
        oa.x = f2bf(p0.x); oa.y = f2bf(p0.y); oa.z = f2bf(p1.x); oa.w = f2bf(p1.y);
        ob.x = f2bf(p2.x); ob.y = f2bf(p2.y); ob.z = f2bf(p3.x); ob.w = f2bf(p3.y);
        *(ushort4*)&Hs2[node * DOUT + es * 8] = oa;
        *(ushort4*)&Hs2[node * DOUT + es * 8 + 4] = ob;
    }
}

// ---------------- gather2 (F=32 bf16): 2 nodes/wave, 8 slots x 4 fgroups, 2-deep + fc --
__global__ __launch_bounds__(256) void gather2_kernel(const int* __restrict__ offs,
                                                      const int* __restrict__ ends,
                                                      const float* __restrict__ dinv,
                                                      const ush* __restrict__ Hs,
                                                      const int* __restrict__ csr,
                                                      const float* __restrict__ b2,
                                                      const float* __restrict__ fcw,
                                                      const float* __restrict__ fcb,
                                                      float* __restrict__ h2,
                                                      float* __restrict__ scores) {
    int wid = (blockIdx.x * 256 + threadIdx.x) >> 6;
    int lane = threadIdx.x & 63;
    int node = wid * 2 + (lane >> 5);
    if (node >= NN) return;
    int l = lane & 31;
    int es = l >> 2;                     // 8 edge slots (stride 8)
    int fg = l & 3;                      // 4 fgroups x 8 bf16 = 16 B
    int start = offs[node], end = ends[node];
    float dv = dinv[node];                                   // hoisted
    uint4 su = *(const uint4*)&Hs[node * DOUT + fg * 8];     // hoisted self-row
    f32x2 ac0 = {0.f, 0.f}, ac1 = {0.f, 0.f}, ac2 = {0.f, 0.f}, ac3 = {0.f, 0.f};
    int k = start + es;
    for (; k + 8 < end; k += 16) {       // 2 independent rows in flight per lane
        int s0 = csr[k], s1 = csr[k + 8];
        uint4 u0 = *(const uint4*)&Hs[s0 * DOUT + fg * 8];
        uint4 u1 = *(const uint4*)&Hs[s1 * DOUT + fg * 8];
        ACCP(u0) ACCP(u1)
    }
    for (; k < end; k += 8) {
        int s = csr[k];
        uint4 u = *(const uint4*)&Hs[s * DOUT + fg * 8];
        ACCP(u)
    }
    // butterfly over es (bits 2,3,4)
    BFLY(4) BFLY(8) BFLY(16)

    float4 ba = *(const float4*)&b2[fg * 8];
    float4 bb = *(const float4*)&b2[fg * 8 + 4];
    f32x2 dvp; dvp.x = dv; dvp.y = dv;
    pka(ac0, up2(su.x)); pka(ac1, up2(su.y)); pka(ac2, up2(su.z)); pka(ac3, up2(su.w));
    f32x2 h0; h0.x = ba.x; h0.y = ba.y;
    f32x2 h1; h1.x = ba.z; h1.y = ba.w;
    f32x2 h2v; h2v.x = bb.x; h2v.y = bb.y;
    f32x2 h3; h3.x = bb.z; h3.y = bb.w;
    pkfma(h0, dvp, ac0); pkfma(h1, dvp, ac1); pkfma(h2v, dvp, ac2); pkfma(h3, dvp, ac3);
    h0.x = fmaxf(h0.x, 0.f); h0.y = fmaxf(h0.y, 0.f);
    h1.x = fmaxf(h1.x, 0.f); h1.y = fmaxf(h1.y, 0.f);
    h2v.x = fmaxf(h2v.x, 0.f); h2v.y = fmaxf(h2v.y, 0.f);
    h3.x = fmaxf(h3.x, 0.f); h3.y = fmaxf(h3.y, 0.f);
    if (es == 0) {
        float4 o0, o1;
        o0.x = h0.x; o0.y = h0.y; o0.z = h1.x; o0.w = h1.y;
        o1.x = h2v.x; o1.y = h2v.y; o1.z = h3.x; o1.w = h3.y;
        *(float4*)&h2[node * DOUT + fg * 8] = o0;
        *(float4*)&h2[node * DOUT + fg * 8 + 4] = o1;
    }
    float4 fa = *(const float4*)&fcw[fg * 8];
    float4 fb = *(const float4*)&fcw[fg * 8 + 4];
    f32x2 dp = {0.f, 0.f};
    f32x2 f01; f01.x = fa.x; f01.y = fa.y;
    f32x2 f23; f23.x = fa.z; f23.y = fa.w;
    f32x2 f45; f45.x = fb.x; f45.y = fb.y;
    f32x2 f67; f67.x = fb.z; f67.y = fb.w;
    pkfma(dp, h0, f01); pkfma(dp, h1, f23); pkfma(dp, h2v, f45); pkfma(dp, h3, f67);
    float sv = dp.x + dp.y;
    sv += __shfl_xor(sv, 1); sv += __shfl_xor(sv, 2);
    if (l == 0) scores[node] = sv + fcb[0];
}

extern "C" void kernel_launch(void* const* d_in, const int* in_sizes, int n_in,
                              void* d_out, int out_size, void* d_ws, size_t ws_size,
                              hipStream_t stream) {
    const float* x   = (const float*)d_in[0];
    const int*   ei  = (const int*)d_in[1];
    const float* W1  = (const float*)d_in[2];
    const float* b1  = (const float*)d_in[3];
    const float* W2  = (const float*)d_in[4];
    const float* b2  = (const float*)d_in[5];
    const float* fcw = (const float*)d_in[6];
    const float* fcb = (const float*)d_in[7];
    const int* src = ei;
    const int* dst = ei + EE;

    float* ws = (float*)d_ws;
    float* dinv    = ws;                          // NN f
    int*   offs    = (int*)(ws + 100352);         // NN
    int*   ends    = (int*)(ws + 200704);         // NN
    int*   bcur    = (int*)(ws + 301056);         // NBUCK
    int*   csr     = (int*)(ws + 301568);         // NBUCK*BCAP
    unsigned* tmp  = (unsigned*)(ws + 2103296);   // NBUCK*BCAP
    ush*   Hs1     = (ush*)(ws + 3905024);        // NN*64 bf16
    ush*   Hs2     = (ush*)(ws + 7105024);        // NN*32 bf16

    float* out    = (float*)d_out;
    float* scores = out;          // NN
    float* h2     = out + NN;     // NN*32

    const int T = 256;
    // CSR build (fixed-capacity bucket binning)
    init_bcur_kernel<<<2, 256, 0, stream>>>(bcur);
    binA_kernel<<<NCHUNK, T, 0, stream>>>(src, dst, bcur, tmp);
    binB_kernel<<<NBUCK, T, 0, stream>>>(tmp, bcur, csr, offs, ends, dinv);
    // layer 1: Hs1 = bf16((x@W1)*dinv)   [MFMA]
    gemm_mfma_kernel<DIN, DH, float><<<(NN + 127) / 128, T, 0, stream>>>(x, W1, dinv, Hs1);
    // layer 1 gather + layer 2 transform fused: Hs2 = bf16((relu(...)@W2)*dinv)
    gather1_fused_kernel<<<(NN / 2 * 64 + T - 1) / T, T, 0, stream>>>(offs, ends, dinv, Hs1, csr, b1, W2, Hs2);
    // layer 2 gather + fc
    gather2_kernel<<<(NN / 2 * 64 + T - 1) / T, T, 0, stream>>>(offs, ends, dinv, Hs2, csr, b2, fcw, fcb, h2, scores);
}

// Round 4
// 214.390 us; speedup vs baseline: 1.0683x; 1.0683x over previous
//
#include <hip/hip_runtime.h>

#define NN 100000
#define EE 1600000
#define DIN 128
#define DH 64
#define DOUT 32

#define BSH 8                      // bucket = dst >> 8  (256 nodes/bucket)
#define BNODES 256
#define NBUCK ((NN + BNODES - 1) / BNODES)   // 391
#define BCAP 4608                  // fixed bucket capacity (mean 4096 + 8 sigma)
#define CHUNK 4096                 // edges per Pass-A workgroup
#define NCHUNK ((EE + CHUNK - 1) / CHUNK)    // 391

typedef unsigned short ush;
typedef __attribute__((ext_vector_type(8))) short bf16x8;
typedef __attribute__((ext_vector_type(4))) float f32x4;
typedef __attribute__((ext_vector_type(2))) float f32x2;

__device__ __forceinline__ float bflo(unsigned u) {
    union { unsigned u; float f; } c; c.u = u << 16; return c.f;
}
__device__ __forceinline__ float bfhi(unsigned u) {
    union { unsigned u; float f; } c; c.u = u & 0xffff0000u; return c.f;
}
__device__ __forceinline__ ush f2bf(float f) {
    union { float f; unsigned u; } c; c.f = f;
    unsigned r = c.u + 0x7fff + ((c.u >> 16) & 1);   // round-to-nearest-even
    return (ush)(r >> 16);
}

// -------- packed dual-f32 ops (CDNA VOP3P: add/mul/fma only — NO pk_max) --------
__device__ __forceinline__ void pka(f32x2& a, f32x2 b) {          // a += b
    asm("v_pk_add_f32 %0, %0, %1" : "+v"(a) : "v"(b));
}
__device__ __forceinline__ void pkfma(f32x2& d, f32x2 a, f32x2 b) { // d += a*b
    asm("v_pk_fma_f32 %0, %1, %2, %0" : "+v"(d) : "v"(a), "v"(b));
}
__device__ __forceinline__ void pkmul(f32x2& a, f32x2 b) {        // a *= b
    asm("v_pk_mul_f32 %0, %0, %1" : "+v"(a) : "v"(b));
}
__device__ __forceinline__ f32x2 up2(unsigned u) {                // (bf16 lo, bf16 hi) -> 2 f32
    f32x2 p; p.x = bflo(u); p.y = bfhi(u); return p;
}

// ---------------- init bucket cursors to fixed bases ----------------
__global__ void init_bcur_kernel(int* __restrict__ bcur) {
    int i = blockIdx.x * 256 + threadIdx.x;
    if (i < NBUCK) bcur[i] = i * BCAP;
}

// ---------------- Pass A: bin edges into fixed-capacity buckets (packed (src<<8)|dstlow)
__global__ __launch_bounds__(256) void binA_kernel(const int* __restrict__ src,
                                                   const int* __restrict__ dst,
                                                   int* __restrict__ bcur,
                                                   unsigned* __restrict__ tmp) {
    __shared__ int hist[NBUCK];
    __shared__ int scn[NBUCK];      // exclusive scan (staging base per bucket)
    __shared__ int cur[NBUCK];      // staging cursor
    __shared__ int gb[NBUCK];       // global base - scn  (addr = gb[b] + lp)
    __shared__ int s2[256];
    __shared__ unsigned staged[CHUNK];
    __shared__ int gaddr[CHUNK];
    int t = threadIdx.x;
    for (int i = t; i < NBUCK; i += 256) hist[i] = 0;
    __syncthreads();
    int e0 = blockIdx.x * CHUNK;
    int nE = min(CHUNK, EE - e0);

    int my_e[16], my_bk[16];
#pragma unroll
    for (int k = 0; k < 16; k++) {
        int li = t + k * 256;
        bool ok = li < nE;
        int idx = ok ? (e0 + li) : e0;
        int d = dst[idx];
        int s = src[idx];
        int b = d >> BSH;
        my_e[k] = (s << 8) | (d & 255);
        my_bk[k] = ok ? b : -1;
        if (ok) atomicAdd(&hist[b], 1);
    }
    __syncthreads();
    int a0 = (2 * t < NBUCK) ? hist[2 * t] : 0;
    int a1 = (2 * t + 1 < NBUCK) ? hist[2 * t + 1] : 0;
    s2[t] = a0 + a1;
    __syncthreads();
    for (int off = 1; off < 256; off <<= 1) {
        int x = (t >= off) ? s2[t - off] : 0;
        __syncthreads();
        s2[t] += x;
        __syncthreads();
    }
    int excl = s2[t] - a0 - a1;
    if (2 * t < NBUCK)     { scn[2 * t] = excl;          cur[2 * t] = excl; }
    if (2 * t + 1 < NBUCK) { scn[2 * t + 1] = excl + a0; cur[2 * t + 1] = excl + a0; }
    __syncthreads();
    for (int i = t; i < NBUCK; i += 256) {
        int h = hist[i];
        if (h) gb[i] = atomicAdd(&bcur[i], h) - scn[i];
    }
    __syncthreads();
#pragma unroll
    for (int k = 0; k < 16; k++) {
        int b = my_bk[k];
        if (b >= 0) {
            int lp = atomicAdd(&cur[b], 1);
            staged[lp] = (unsigned)my_e[k];
            gaddr[lp] = gb[b] + lp;
        }
    }
    __syncthreads();
    for (int i = t; i < nE; i += 256)
        tmp[gaddr[i]] = staged[i];
}

// ---------------- Pass B: per-bucket node histogram + scan -> offs/ends/dinv/csr -------
__global__ __launch_bounds__(256) void binB_kernel(const unsigned* __restrict__ tmp,
                                                   const int* __restrict__ bcur,
                                                   int* __restrict__ csr,
                                                   int* __restrict__ offs,
                                                   int* __restrict__ ends,
                                                   float* __restrict__ dinv) {
    __shared__ int hist[BNODES], cur[BNODES], sc[BNODES];
    int b = blockIdx.x, t = threadIdx.x;
    int e0 = b * BCAP, e1 = bcur[b];
    hist[t] = 0;
    __syncthreads();
    for (int i = e0 + t; i < e1; i += 256) atomicAdd(&hist[tmp[i] & 255], 1);
    __syncthreads();
    int v = hist[t];
    sc[t] = v;
    __syncthreads();
    for (int off = 1; off < 256; off <<= 1) {
        int x = (t >= off) ? sc[t - off] : 0;
        __syncthreads();
        sc[t] += x;
        __syncthreads();
    }
    int excl = sc[t] - v;
    cur[t] = e0 + excl;
    int node = (b << BSH) + t;
    if (node < NN) {
        offs[node] = e0 + excl;
        ends[node] = e0 + excl + v;
        dinv[node] = 1.0f / sqrtf((float)v + 1.0f);
    }
    __syncthreads();
    for (int i = e0 + t; i < e1; i += 256) {
        unsigned u = tmp[i];
        int pos = atomicAdd(&cur[u & 255], 1);
        csr[pos] = (int)(u >> 8);
    }
}

// ---------------- MFMA GEMM + dinv-scale, bf16 out: Y = bf16((X@W)*dinv) -------------
template <int K, int NC, typename XT>
__global__ __launch_bounds__(256) void gemm_mfma_kernel(const XT* __restrict__ X,
                                                        const float* __restrict__ W,
                                                        const float* __restrict__ dinv,
                                                        ush* __restrict__ Y) {
    constexpr int GROWS = 128;
    constexpr int KP = K + 8;            // pad: row stride odd multiple of 16B
    constexpr int NKC = K / 32;          // k-chunks
    constexpr int NCT = NC / 16;         // col tiles
    __shared__ __align__(16) ush Xl[GROWS * KP];
    __shared__ __align__(16) ush Wt[NC * KP];
    const int t = threadIdx.x;
    const int row0 = blockIdx.x * GROWS;

    if constexpr (sizeof(XT) == 4) {
        for (int i = t; i < GROWS * (K / 4); i += 256) {
            int r = i / (K / 4), c4 = i % (K / 4);
            int row = row0 + r;
            float4 v = make_float4(0.f, 0.f, 0.f, 0.f);
            if (row < NN) v = *(const float4*)&X[(size_t)row * K + c4 * 4];
            ushort4 o;
            o.x = f2bf(v.x); o.y = f2bf(v.y); o.z = f2bf(v.z); o.w = f2bf(v.w);
            *(ushort4*)&Xl[r * KP + c4 * 4] = o;
        }
    } else {
        for (int i = t; i < GROWS * (K / 8); i += 256) {
            int r = i / (K / 8), c8 = i % (K / 8);
            int row = row0 + r;
            uint4 v = make_uint4(0, 0, 0, 0);
            if (row < NN) v = *(const uint4*)&X[(size_t)row * K + c8 * 8];
            *(uint4*)&Xl[r * KP + c8 * 8] = v;
        }
    }
    for (int i = t; i < K * (NC / 4); i += 256) {
        int k = i / (NC / 4), n4 = i % (NC / 4);
        float4 v = *(const float4*)&W[k * NC + n4 * 4];
        Wt[(n4 * 4 + 0) * KP + k] = f2bf(v.x);
        Wt[(n4 * 4 + 1) * KP + k] = f2bf(v.y);
        Wt[(n4 * 4 + 2) * KP + k] = f2bf(v.z);
        Wt[(n4 * 4 + 3) * KP + k] = f2bf(v.w);
    }
    __syncthreads();

    const int wave = t >> 6, lane = t & 63;
    const int m = lane & 15, quad = lane >> 4;
    const int wrow = wave * 32;

    f32x4 acc[2][NCT];
#pragma unroll
    for (int rt = 0; rt < 2; rt++)
#pragma unroll
        for (int ct = 0; ct < NCT; ct++) acc[rt][ct] = (f32x4){0.f, 0.f, 0.f, 0.f};

#pragma unroll
    for (int kc = 0; kc < NKC; kc++) {
        int koff = kc * 32 + quad * 8;
        bf16x8 b[NCT];
#pragma unroll
        for (int ct = 0; ct < NCT; ct++)
            b[ct] = *(const bf16x8*)&Wt[(ct * 16 + m) * KP + koff];
#pragma unroll
        for (int rt = 0; rt < 2; rt++) {
            bf16x8 a = *(const bf16x8*)&Xl[(wrow + rt * 16 + m) * KP + koff];
#pragma unroll
            for (int ct = 0; ct < NCT; ct++)
                acc[rt][ct] = __builtin_amdgcn_mfma_f32_16x16x32_bf16(a, b[ct], acc[rt][ct], 0, 0, 0);
        }
    }
#pragma unroll
    for (int rt = 0; rt < 2; rt++) {
#pragma unroll
        for (int reg = 0; reg < 4; reg++) {
            int row = row0 + wrow + rt * 16 + quad * 4 + reg;
            if (row < NN) {
                float s = dinv[row];
#pragma unroll
                for (int ct = 0; ct < NCT; ct++)
                    Y[(size_t)row * NC + ct * 16 + m] = f2bf(acc[rt][ct][reg] * s);
            }
        }
    }
}

// packed accumulate of a 4-uint (8 bf16) row chunk into 4 f32x2 accumulators
#define ACCP(u4) { pka(ac0, up2(u4.x)); pka(ac1, up2(u4.y)); \
                   pka(ac2, up2(u4.z)); pka(ac3, up2(u4.w)); }

// zero an invalid batch's row before accumulation (v_cndmask x4)
#define ZINV(u4, v) { u4.x = (v) ? u4.x : 0u; u4.y = (v) ? u4.y : 0u; \
                      u4.z = (v) ? u4.z : 0u; u4.w = (v) ? u4.w : 0u; }

#define BFLY(msk) { f32x2 t_;                                           \
    t_.x = __shfl_xor(ac0.x, msk); t_.y = __shfl_xor(ac0.y, msk); pka(ac0, t_); \
    t_.x = __shfl_xor(ac1.x, msk); t_.y = __shfl_xor(ac1.y, msk); pka(ac1, t_); \
    t_.x = __shfl_xor(ac2.x, msk); t_.y = __shfl_xor(ac2.y, msk); pka(ac2, t_); \
    t_.x = __shfl_xor(ac3.x, msk); t_.y = __shfl_xor(ac3.y, msk); pka(ac3, t_); }

// ---------------- gather1 + gemm2 fused (F=64 bf16): 2 nodes/wave, 4 slots x 8 fgroups.
// Latency fix: ALL csr loads are address-independent of each other, so issue 6
// predicated batches upfront (covers deg<=24, ~98% of Poisson(16) nodes with zero
// serial chaining): offs -> 6x csr -> 6x row is a 3-level chain instead of up to
// 8 chained latencies in the old serial tail. Invalid slots clamp to csr[0] and
// the loaded row is zeroed via cndmask.
__global__ __launch_bounds__(256) void gather1_fused_kernel(const int* __restrict__ offs,
                                                            const int* __restrict__ ends,
                                                            const float* __restrict__ dinv,
                                                            const ush* __restrict__ Hs,
                                                            const int* __restrict__ csr,
                                                            const float* __restrict__ b1,
                                                            const float* __restrict__ W2,
                                                            ush* __restrict__ Hs2) {
    // lane l (=lane&31, fg=l&7, es=l>>3) owns W2 rows fg*8..+8, cols es*8..+8 as a
    // contiguous 64-float block; stride 68 floats (272B) staggers lanes across banks.
    __shared__ __align__(16) float Wp[32 * 68];
    {
        int t = threadIdx.x;            // 2048 floats / 256 threads = 8 floats each
        int lp = t >> 3, r = t & 7;
        int srow = (lp & 7) * 8 + r, scol = (lp >> 3) * 8;
        float4 va = *(const float4*)&W2[srow * DOUT + scol];
        float4 vb = *(const float4*)&W2[srow * DOUT + scol + 4];
        *(float4*)&Wp[lp * 68 + r * 8] = va;
        *(float4*)&Wp[lp * 68 + r * 8 + 4] = vb;
    }
    __syncthreads();

    int wid = (blockIdx.x * 256 + threadIdx.x) >> 6;
    int lane = threadIdx.x & 63;
    int node = wid * 2 + (lane >> 5);
    if (node >= NN) return;
    int l = lane & 31;
    int es = l >> 3;                     // 4 edge slots (stride 4)
    int fg = l & 7;                      // 8 fgroups x 8 bf16 = 16 B
    int start = offs[node], end = ends[node];
    float dv = dinv[node];                                   // hoisted
    uint4 su = *(const uint4*)&Hs[node * DH + fg * 8];       // hoisted self-row
    f32x2 ac0 = {0.f, 0.f}, ac1 = {0.f, 0.f}, ac2 = {0.f, 0.f}, ac3 = {0.f, 0.f};

    int base = start + es;
    {   // 6 predicated batches, all loads in flight together (covers deg<=24)
        int p0 = base, p1 = base + 4, p2 = base + 8,
            p3 = base + 12, p4 = base + 16, p5 = base + 20;
        bool v0 = p0 < end, v1 = p1 < end, v2 = p2 < end,
             v3 = p3 < end, v4 = p4 < end, v5 = p5 < end;
        int s0 = csr[v0 ? p0 : 0], s1 = csr[v1 ? p1 : 0], s2 = csr[v2 ? p2 : 0],
            s3 = csr[v3 ? p3 : 0], s4 = csr[v4 ? p4 : 0], s5 = csr[v5 ? p5 : 0];
        uint4 u0 = *(const uint4*)&Hs[s0 * DH + fg * 8];
        uint4 u1 = *(const uint4*)&Hs[s1 * DH + fg * 8];
        uint4 u2 = *(const uint4*)&Hs[s2 * DH + fg * 8];
        uint4 u3 = *(const uint4*)&Hs[s3 * DH + fg * 8];
        uint4 u4 = *(const uint4*)&Hs[s4 * DH + fg * 8];
        uint4 u5 = *(const uint4*)&Hs[s5 * DH + fg * 8];
        ZINV(u0, v0) ZINV(u1, v1) ZINV(u2, v2)
        ZINV(u3, v3) ZINV(u4, v4) ZINV(u5, v5)
        ACCP(u0) ACCP(u1) ACCP(u2) ACCP(u3) ACCP(u4) ACCP(u5)
    }
    for (int k = base + 24; k < end; k += 4) {   // rare overflow (deg>24, ~2%)
        int s = csr[k];
        uint4 u = *(const uint4*)&Hs[s * DH + fg * 8];
        ACCP(u)
    }
    // butterfly over es (bits 3,4): every lane gets full neighbor sums for its fgroup
    BFLY(8) BFLY(16)

    float4 ba = *(const float4*)&b1[fg * 8];
    float4 bb = *(const float4*)&b1[fg * 8 + 4];
    f32x2 dvp; dvp.x = dv; dvp.y = dv;
    // h = relu(dv*(acc + self) + b1), pure f32 (no bf16 roundtrip)
    pka(ac0, up2(su.x)); pka(ac1, up2(su.y)); pka(ac2, up2(su.z)); pka(ac3, up2(su.w));
    f32x2 h0; h0.x = ba.x; h0.y = ba.y;
    f32x2 h1; h1.x = ba.z; h1.y = ba.w;
    f32x2 h2; h2.x = bb.x; h2.y = bb.y;
    f32x2 h3; h3.x = bb.z; h3.y = bb.w;
    pkfma(h0, dvp, ac0); pkfma(h1, dvp, ac1); pkfma(h2, dvp, ac2); pkfma(h3, dvp, ac3);
    h0.x = fmaxf(h0.x, 0.f); h0.y = fmaxf(h0.y, 0.f);
    h1.x = fmaxf(h1.x, 0.f); h1.y = fmaxf(h1.y, 0.f);
    h2.x = fmaxf(h2.x, 0.f); h2.y = fmaxf(h2.y, 0.f);
    h3.x = fmaxf(h3.x, 0.f); h3.y = fmaxf(h3.y, 0.f);

    // per-lane 8x8 block of h1@W2: p[c-pair] += h[r] * W2[fg*8+r][es*8 + c-pair]
    const float* wl = &Wp[l * 68];
    float hs_[8] = {h0.x, h0.y, h1.x, h1.y, h2.x, h2.y, h3.x, h3.y};
    f32x2 p0 = {0.f, 0.f}, p1 = {0.f, 0.f}, p2 = {0.f, 0.f}, p3 = {0.f, 0.f};
#pragma unroll
    for (int r = 0; r < 8; r++) {
        float4 wa = *(const float4*)&wl[r * 8];
        float4 wb = *(const float4*)&wl[r * 8 + 4];
        f32x2 hr; hr.x = hs_[r]; hr.y = hs_[r];
        f32x2 w01; w01.x = wa.x; w01.y = wa.y;
        f32x2 w23; w23.x = wa.z; w23.y = wa.w;
        f32x2 w45; w45.x = wb.x; w45.y = wb.y;
        f32x2 w67; w67.x = wb.z; w67.y = wb.w;
        pkfma(p0, hr, w01); pkfma(p1, hr, w23);
        pkfma(p2, hr, w45); pkfma(p3, hr, w67);
    }
    // butterfly over fg (bits 0..2): full column sums on every lane
#pragma unroll
    for (int msk = 1; msk <= 4; msk <<= 1) {
        f32x2 t_;
        t_.x = __shfl_xor(p0.x, msk); t_.y = __shfl_xor(p0.y, msk); pka(p0, t_);
        t_.x = __shfl_xor(p1.x, msk); t_.y = __shfl_xor(p1.y, msk); pka(p1, t_);
        t_.x = __shfl_xor(p2.x, msk); t_.y = __shfl_xor(p2.y, msk); pka(p2, t_);
        t_.x = __shfl_xor(p3.x, msk); t_.y = __shfl_xor(p3.y, msk); pka(p3, t_);
    }
    if (fg == 0) {
        pkmul(p0, dvp); pkmul(p1, dvp); pkmul(p2, dvp); pkmul(p3, dvp);
        ushort4 oa, ob;
        oa.x = f2bf(p0.x); oa.y = f2bf(p0.y); oa.z = f2bf(p1.x); oa.w = f2bf(p1.y);
        ob.x = f2bf(p2.x); ob.y = f2bf(p2.y); ob.z = f2bf(p3.x); ob.w = f2bf(p3.y);
        *(ushort4*)&Hs2[node * DOUT + es * 8] = oa;
        *(ushort4*)&Hs2[node * DOUT + es * 8 + 4] = ob;
    }
}

// ---------------- gather2 (F=32 bf16): 2 nodes/wave, 8 slots x 4 fgroups + fc ----------
// Same latency fix: 4 predicated upfront batches cover deg<=32 (P(tail) ~ 2e-4).
__global__ __launch_bounds__(256) void gather2_kernel(const int* __restrict__ offs,
                                                      const int* __restrict__ ends,
                                                      const float* __restrict__ dinv,
                                                      const ush* __restrict__ Hs,
                                                      const int* __restrict__ csr,
                                                      const float* __restrict__ b2,
                                                      const float* __restrict__ fcw,
                                                      const float* __restrict__ fcb,
                                                      float* __restrict__ h2,
                                                      float* __restrict__ scores) {
    int wid = (blockIdx.x * 256 + threadIdx.x) >> 6;
    int lane = threadIdx.x & 63;
    int node = wid * 2 + (lane >> 5);
    if (node >= NN) return;
    int l = lane & 31;
    int es = l >> 2;                     // 8 edge slots (stride 8)
    int fg = l & 3;                      // 4 fgroups x 8 bf16 = 16 B
    int start = offs[node], end = ends[node];
    float dv = dinv[node];                                   // hoisted
    uint4 su = *(const uint4*)&Hs[node * DOUT + fg * 8];     // hoisted self-row
    f32x2 ac0 = {0.f, 0.f}, ac1 = {0.f, 0.f}, ac2 = {0.f, 0.f}, ac3 = {0.f, 0.f};

    int base = start + es;
    {   // 4 predicated batches, all loads in flight together (covers deg<=32)
        int p0 = base, p1 = base + 8, p2 = base + 16, p3 = base + 24;
        bool v0 = p0 < end, v1 = p1 < end, v2 = p2 < end, v3 = p3 < end;
        int s0 = csr[v0 ? p0 : 0], s1 = csr[v1 ? p1 : 0],
            s2 = csr[v2 ? p2 : 0], s3 = csr[v3 ? p3 : 0];
        uint4 u0 = *(const uint4*)&Hs[s0 * DOUT + fg * 8];
        uint4 u1 = *(const uint4*)&Hs[s1 * DOUT + fg * 8];
        uint4 u2 = *(const uint4*)&Hs[s2 * DOUT + fg * 8];
        uint4 u3 = *(const uint4*)&Hs[s3 * DOUT + fg * 8];
        ZINV(u0, v0) ZINV(u1, v1) ZINV(u2, v2) ZINV(u3, v3)
        ACCP(u0) ACCP(u1) ACCP(u2) ACCP(u3)
    }
    for (int k = base + 32; k < end; k += 8) {   // ultra-rare overflow (deg>32)
        int s = csr[k];
        uint4 u = *(const uint4*)&Hs[s * DOUT + fg * 8];
        ACCP(u)
    }
    // butterfly over es (bits 2,3,4)
    BFLY(4) BFLY(8) BFLY(16)

    float4 ba = *(const float4*)&b2[fg * 8];
    float4 bb = *(const float4*)&b2[fg * 8 + 4];
    f32x2 dvp; dvp.x = dv; dvp.y = dv;
    pka(ac0, up2(su.x)); pka(ac1, up2(su.y)); pka(ac2, up2(su.z)); pka(ac3, up2(su.w));
    f32x2 h0; h0.x = ba.x; h0.y = ba.y;
    f32x2 h1; h1.x = ba.z; h1.y = ba.w;
    f32x2 h2v; h2v.x = bb.x; h2v.y = bb.y;
    f32x2 h3; h3.x = bb.z; h3.y = bb.w;
    pkfma(h0, dvp, ac0); pkfma(h1, dvp, ac1); pkfma(h2v, dvp, ac2); pkfma(h3, dvp, ac3);
    h0.x = fmaxf(h0.x, 0.f); h0.y = fmaxf(h0.y, 0.f);
    h1.x = fmaxf(h1.x, 0.f); h1.y = fmaxf(h1.y, 0.f);
    h2v.x = fmaxf(h2v.x, 0.f); h2v.y = fmaxf(h2v.y, 0.f);
    h3.x = fmaxf(h3.x, 0.f); h3.y = fmaxf(h3.y, 0.f);
    if (es == 0) {
        float4 o0, o1;
        o0.x = h0.x; o0.y = h0.y; o0.z = h1.x; o0.w = h1.y;
        o1.x = h2v.x; o1.y = h2v.y; o1.z = h3.x; o1.w = h3.y;
        *(float4*)&h2[node * DOUT + fg * 8] = o0;
        *(float4*)&h2[node * DOUT + fg * 8 + 4] = o1;
    }
    float4 fa = *(const float4*)&fcw[fg * 8];
    float4 fb = *(const float4*)&fcw[fg * 8 + 4];
    f32x2 dp = {0.f, 0.f};
    f32x2 f01; f01.x = fa.x; f01.y = fa.y;
    f32x2 f23; f23.x = fa.z; f23.y = fa.w;
    f32x2 f45; f45.x = fb.x; f45.y = fb.y;
    f32x2 f67; f67.x = fb.z; f67.y = fb.w;
    pkfma(dp, h0, f01); pkfma(dp, h1, f23); pkfma(dp, h2v, f45); pkfma(dp, h3, f67);
    float sv = dp.x + dp.y;
    sv += __shfl_xor(sv, 1); sv += __shfl_xor(sv, 2);
    if (l == 0) scores[node] = sv + fcb[0];
}

extern "C" void kernel_launch(void* const* d_in, const int* in_sizes, int n_in,
                              void* d_out, int out_size, void* d_ws, size_t ws_size,
                              hipStream_t stream) {
    const float* x   = (const float*)d_in[0];
    const int*   ei  = (const int*)d_in[1];
    const float* W1  = (const float*)d_in[2];
    const float* b1  = (const float*)d_in[3];
    const float* W2  = (const float*)d_in[4];
    const float* b2  = (const float*)d_in[5];
    const float* fcw = (const float*)d_in[6];
    const float* fcb = (const float*)d_in[7];
    const int* src = ei;
    const int* dst = ei + EE;

    float* ws = (float*)d_ws;
    float* dinv    = ws;                          // NN f
    int*   offs    = (int*)(ws + 100352);         // NN
    int*   ends    = (int*)(ws + 200704);         // NN
    int*   bcur    = (int*)(ws + 301056);         // NBUCK
    int*   csr     = (int*)(ws + 301568);         // NBUCK*BCAP
    unsigned* tmp  = (unsigned*)(ws + 2103296);   // NBUCK*BCAP
    ush*   Hs1     = (ush*)(ws + 3905024);        // NN*64 bf16
    ush*   Hs2     = (ush*)(ws + 7105024);        // NN*32 bf16

    float* out    = (float*)d_out;
    float* scores = out;          // NN
    float* h2     = out + NN;     // NN*32

    const int T = 256;
    // CSR build (fixed-capacity bucket binning)
    init_bcur_kernel<<<2, 256, 0, stream>>>(bcur);
    binA_kernel<<<NCHUNK, T, 0, stream>>>(src, dst, bcur, tmp);
    binB_kernel<<<NBUCK, T, 0, stream>>>(tmp, bcur, csr, offs, ends, dinv);
    // layer 1: Hs1 = bf16((x@W1)*dinv)   [MFMA]
    gemm_mfma_kernel<DIN, DH, float><<<(NN + 127) / 128, T, 0, stream>>>(x, W1, dinv, Hs1);
    // layer 1 gather + layer 2 transform fused: Hs2 = bf16((relu(...)@W2)*dinv)
    gather1_fused_kernel<<<(NN / 2 * 64 + T - 1) / T, T, 0, stream>>>(offs, ends, dinv, Hs1, csr, b1, W2, Hs2);
    // layer 2 gather + fc
    gather2_kernel<<<(NN / 2 * 64 + T - 1) / T, T, 0, stream>>>(offs, ends, dinv, Hs2, csr, b2, fcw, fcb, h2, scores);
}